// Round 3
// baseline (396.697 us; speedup 1.0000x reference)
//
#include <hip/hip_runtime.h>
#include <math.h>

// Problem constants
#define NROWS 16384   // 32*512
#define H     768
#define KEXP  6912    // 768 (silu*base_w) + 768*8 (bases*spline_w*scaler)
#define NCHUNK 108    // KEXP/64 K-steps
#define NITER 54      // 2 K-steps per 8-phase iteration

typedef __attribute__((ext_vector_type(8))) short  bhalf8;
typedef __attribute__((ext_vector_type(4))) float  floatx4;

__device__ __forceinline__ unsigned short f2bf(float f) {
    unsigned int u = __float_as_uint(f);
    u = (u + 0x7FFFu + ((u >> 16) & 1u)) >> 16;   // RNE
    return (unsigned short)u;
}
__device__ __forceinline__ float bf2f(unsigned short h) {
    return __uint_as_float(((unsigned int)h) << 16);
}
__device__ __forceinline__ unsigned int pack2(unsigned short a, unsigned short b) {
    return (unsigned int)a | ((unsigned int)b << 16);
}
__device__ __forceinline__ float silu_f(float x) { return x / (1.0f + __expf(-x)); }

// Branch-free tanh-form GELU (|err vs exact erf-GELU| < ~1e-3 in u)
__device__ __forceinline__ float gelu_fast(float x) {
    float x3 = x * x * x;
    float y = fmaf(x3, 0.0356774081f, x * 0.7978845608f);
    float e = __expf(2.0f * y);
    float th = 1.0f - 2.0f / (e + 1.0f);
    return 0.5f * x * (1.0f + th);
}

// Closed-form cubic B-spline bases on uniform knots g[j] = (j-3)*0.4 - 1.
__device__ __forceinline__ void kan_bases(float x, float* __restrict__ b) {
    const float c6 = 0.166666666667f;
    float u  = fmaf(x, 2.5f, 5.5f);
    float fj = floorf(u);
    float t  = u - fj;
    int  j0  = (int)fj;
    float t2 = t * t, t3 = t2 * t;
    float n0 = t3 * c6;
    float n1 = fmaf(t3, -0.5f, fmaf(t2, 0.5f, fmaf(t, 0.5f, c6)));
    float n2 = fmaf(t3, 0.5f, fmaf(t2, -1.0f, 0.666666666667f));
    float omt = 1.0f - t;
    float n3 = omt * omt * omt * c6;
#pragma unroll
    for (int c = 0; c < 8; ++c) {
        int d = j0 - c;
        float v = (d == 0) ? n0 : 0.0f;
        v = (d == 1) ? n1 : v;
        v = (d == 2) ? n2 : v;
        v = (d == 3) ? n3 : v;
        b[c] = v;
    }
}

// ---- prep_flat: one thread per x element for F (blocks 0..49151, 3 per row);
//      wp blocks 49152..49919 (one per output neuron, original code).
//      No LDS, no syncthreads, pure streaming: read f32, write 2B + 16B coalesced.
__global__ __launch_bounds__(256) void prep_flat(
    const float* __restrict__ x, const float* __restrict__ bw,
    const float* __restrict__ sw, const float* __restrict__ sc,
    unsigned short* __restrict__ wp, unsigned short* __restrict__ F)
{
    const int b = blockIdx.x, t = threadIdx.x;
    if (b < 3 * NROWS) {
        const int n = b / 3;
        const int seg = b - n * 3;
        const int i = seg * 256 + t;
        float xv = x[(size_t)n * H + i];
        unsigned short* out = F + (size_t)n * KEXP;
        out[i] = f2bf(silu_f(xv));                 // 2B store, coalesced
        float bb[8];
        kan_bases(xv, bb);
        uint4 pk;
        pk.x = pack2(f2bf(bb[0]), f2bf(bb[1]));
        pk.y = pack2(f2bf(bb[2]), f2bf(bb[3]));
        pk.z = pack2(f2bf(bb[4]), f2bf(bb[5]));
        pk.w = pack2(f2bf(bb[6]), f2bf(bb[7]));
        *(uint4*)(out + H + (size_t)i * 8) = pk;   // 16B store, coalesced
    } else {
        const int n = b - 3 * NROWS;               // 0..767
        const float* bwr = bw + (size_t)n * H;
        unsigned short* out = wp + (size_t)n * KEXP;
        if (t < 96) {
            const float4* xp = (const float4*)(bwr + t * 8);
            float4 v0 = xp[0], v1 = xp[1];
            uint4 pk;
            pk.x = pack2(f2bf(v0.x), f2bf(v0.y));
            pk.y = pack2(f2bf(v0.z), f2bf(v0.w));
            pk.z = pack2(f2bf(v1.x), f2bf(v1.y));
            pk.w = pack2(f2bf(v1.z), f2bf(v1.w));
            *(uint4*)(out + t * 8) = pk;
        }
#pragma unroll
        for (int p = 0; p < 3; ++p) {
            int i = t + p * 256;
            float s = sc[(size_t)n * H + i];
            const float4* swp = (const float4*)(sw + ((size_t)n * H + i) * 8);
            float4 w0 = swp[0], w1 = swp[1];
            uint4 pk;
            pk.x = pack2(f2bf(w0.x * s), f2bf(w0.y * s));
            pk.y = pack2(f2bf(w0.z * s), f2bf(w0.w * s));
            pk.z = pack2(f2bf(w1.x * s), f2bf(w1.y * s));
            pk.w = pack2(f2bf(w1.z * s), f2bf(w1.w * s));
            *(uint4*)(out + H + (size_t)i * 8) = pk;
        }
    }
}

// ==== Layer 1: 256x192 8-phase bf16 GEMM, grid = 256 blocks = 1/CU ====
// (unchanged from round 2 — 157us, MfmaUtil 47%, 0 bank conflicts)

#define AS1 __attribute__((address_space(1)))
#define AS3 __attribute__((address_space(3)))

#define DSR(D, A, O) asm volatile("ds_read_b128 %0, %1 offset:" #O : "=v"(D) : "v"(A) : "memory")
#define LDA0(O) do{ DSR(fA0[0],avA[0],O); DSR(fA0[1],avA[1],O); DSR(fA0[2],avA[2],O); DSR(fA0[3],avA[3],O); \
                    DSR(fA0[4],avA[4],O); DSR(fA0[5],avA[5],O); DSR(fA0[6],avA[6],O); DSR(fA0[7],avA[7],O); }while(0)
#define LDA1(O) do{ DSR(fA1[0],avA[0],O); DSR(fA1[1],avA[1],O); DSR(fA1[2],avA[2],O); DSR(fA1[3],avA[3],O); \
                    DSR(fA1[4],avA[4],O); DSR(fA1[5],avA[5],O); DSR(fA1[6],avA[6],O); DSR(fA1[7],avA[7],O); }while(0)
#define LDB(O)  do{ DSR(fB[0],avB[0],O); DSR(fB[1],avB[1],O); }while(0)

#define MM0(QN) do{ \
    _Pragma("unroll") \
    for (int kk = 0; kk < 2; ++kk) \
        _Pragma("unroll") \
        for (int im = 0; im < 4; ++im) \
            acc0[QN][im] = __builtin_amdgcn_mfma_f32_16x16x32_bf16( \
                fA0[im*2+kk], fB[kk], acc0[QN][im], 0, 0, 0); \
}while(0)
#define MM1(QN) do{ \
    _Pragma("unroll") \
    for (int kk = 0; kk < 2; ++kk) \
        _Pragma("unroll") \
        for (int im = 0; im < 4; ++im) \
            acc1[QN][im] = __builtin_amdgcn_mfma_f32_16x16x32_bf16( \
                fA1[im*2+kk], fB[kk], acc1[QN][im], 0, 0, 0); \
}while(0)

#define STG_A(BF,HH,KS) do{ \
    __builtin_amdgcn_global_load_lds((const AS1 void*)(pA##HH[0] + (size_t)(KS)*64), \
        (AS3 void*)&sA[BF][HH][wb8], 16, 0, 0); \
    __builtin_amdgcn_global_load_lds((const AS1 void*)(pA##HH[1] + (size_t)(KS)*64), \
        (AS3 void*)&sA[BF][HH][4096 + wb8], 16, 0, 0); \
}while(0)
#define STG_B(BF,QN,KS) \
    __builtin_amdgcn_global_load_lds((const AS1 void*)(pB[QN] + (size_t)(KS)*64), \
        (AS3 void*)&sB[BF][QN][wb8], 16, 0, 0)

#define PH_MID do{ __builtin_amdgcn_s_barrier(); \
    asm volatile("s_waitcnt lgkmcnt(0)" ::: "memory"); \
    __builtin_amdgcn_sched_barrier(0); \
    __builtin_amdgcn_s_setprio(1); }while(0)
#define PH_END do{ __builtin_amdgcn_s_setprio(0); \
    __builtin_amdgcn_sched_barrier(0); \
    __builtin_amdgcn_s_barrier(); }while(0)
#define PH_END_VMN(N) do{ __builtin_amdgcn_s_setprio(0); \
    __builtin_amdgcn_sched_barrier(0); \
    asm volatile("s_waitcnt vmcnt(" #N ")" ::: "memory"); \
    __builtin_amdgcn_s_barrier(); }while(0)

__global__ __launch_bounds__(512, 2) void kan1_gemm(
    const unsigned short* __restrict__ F, const unsigned short* __restrict__ wp,
    unsigned short* __restrict__ l1)
{
    __shared__ __align__(16) unsigned short sA[2][2][8192];  // [buf][half 128rows][128*64]
    __shared__ __align__(16) unsigned short sB[2][3][4096];  // [buf][third 64rows][64*64]

    const int b = blockIdx.x;                  // 0..255
    const int s = b >> 3;
    const int rowT = (b & 7) * 8 + (s >> 2);   // 0..63
    const int colT = s & 3;                    // 0..3
    const int rowBase = rowT * 256, colBase = colT * 192;

    const int t = threadIdx.x;
    const int lane = t & 63;
    const int quad = lane >> 4, lm = lane & 15, p7 = lane & 7;
    const int wv = t >> 6, wr = wv & 1, wc = wv >> 1;   // 2M x 4N wave grid

    const int rr = t >> 3;                    // 0..63
    const int slotx = (t & 7) ^ (rr & 7);
    const int wb8 = (t & 448) * 8;            // wave-uniform LDS elem base (wv*512)

    const unsigned short* pA0[2]; const unsigned short* pA1[2];
    const unsigned short* pB[3];
#pragma unroll
    for (int p = 0; p < 2; ++p) {
        pA0[p] = F + (size_t)(rowBase +       p*64 + rr) * KEXP + slotx*8;
        pA1[p] = F + (size_t)(rowBase + 128 + p*64 + rr) * KEXP + slotx*8;
    }
#pragma unroll
    for (int q = 0; q < 3; ++q)
        pB[q] = wp + (size_t)(colBase + q*64 + rr) * KEXP + slotx*8;

    unsigned int avA[8], avB[2];
    {
        unsigned int aB = (unsigned int)(size_t)(AS3 unsigned short*)&sA[0][0][0];
        unsigned int bB = (unsigned int)(size_t)(AS3 unsigned short*)&sB[0][0][0];
#pragma unroll
        for (int im = 0; im < 4; ++im)
#pragma unroll
            for (int kk = 0; kk < 2; ++kk)
                avA[im*2+kk] = aB + (unsigned)(((wr*64 + im*16 + lm)*64 + (((kk*4+quad)^p7)*8)) * 2);
#pragma unroll
        for (int kk = 0; kk < 2; ++kk)
            avB[kk] = bB + (unsigned)(((wc*16 + lm)*64 + (((kk*4+quad)^p7)*8)) * 2);
    }

    floatx4 acc0[3][4] = {};   // [qn][im], qm=0 rows
    floatx4 acc1[3][4] = {};   // qm=1 rows
    bhalf8 fA0[8], fA1[8], fB[2];

    STG_A(0,0,0); STG_A(0,1,0); STG_B(0,0,0); STG_B(0,1,0); STG_B(0,2,0);
    STG_A(1,0,1); STG_A(1,1,1); STG_B(1,0,1); STG_B(1,1,1);
    asm volatile("s_waitcnt vmcnt(8)" ::: "memory");
    __builtin_amdgcn_s_barrier();

#pragma unroll 1
    for (int i = 0; i < NITER; ++i) {
        const int k1 = 2*i + 1;
        const int k2 = (2*i + 2 > 107) ? 107 : 2*i + 2;
        const int k3 = (2*i + 3 > 107) ? 107 : 2*i + 3;
        // K-step 2i from buf0
        LDA0(0);     LDB(0);     STG_B(1,2,k1);               PH_MID; MM0(0);         PH_END_VMN(10);
        LDA1(16384);             STG_A(0,0,k2);               PH_MID; MM1(0);         PH_END_VMN(10);
        LDB(8192);               STG_A(0,1,k2);               PH_MID; MM1(1); MM0(1); PH_END_VMN(11);
        LDB(16384);              STG_B(0,0,k2); STG_B(0,1,k2);PH_MID; MM0(2); MM1(2); PH_END_VMN(8);
        // K-step 2i+1 from buf1
        LDA0(32768); LDB(24576); STG_B(0,2,k2);               PH_MID; MM0(0);         PH_END;
        LDA1(49152);             STG_A(1,0,k3);               PH_MID; MM1(0);         PH_END_VMN(10);
        LDB(32768);              STG_A(1,1,k3);               PH_MID; MM1(1); MM0(1); PH_END_VMN(11);
        LDB(40960);              STG_B(1,0,k3); STG_B(1,1,k3);PH_MID; MM0(2); MM1(2); PH_END_VMN(8);
    }

#pragma unroll
    for (int qn = 0; qn < 3; ++qn)
#pragma unroll
    for (int im = 0; im < 4; ++im) {
        const int col = colBase + qn*64 + wc*16 + lm;
        {
            const int row0 = rowBase + wr*64 + im*16 + quad*4;
#pragma unroll
            for (int rg = 0; rg < 4; ++rg)
                l1[(size_t)(row0 + rg) * H + col] = f2bf(acc0[qn][im][rg]);
        }
        {
            const int row0 = rowBase + 128 + wr*64 + im*16 + quad*4;
#pragma unroll
            for (int rg = 0; rg < 4; ++rg)
                l1[(size_t)(row0 + rg) * H + col] = f2bf(acc1[qn][im][rg]);
        }
    }
}

// ---- Layer 2: LDS-staged pre-scaled bf16 weights, 16 rows/block (1024 blocks).
// sW chunks are 16B per (o,i): lane stride 16B => perfect 8-lanes-per-bank-set,
// conflict-free ds_read_b128. sB2 packs (bw2[0][i],bw2[1][i]) bf16 in 4B: stride-4B
// b32 reads, conflict-free. Scaler folded into sW at staging.
#define R2 16
__global__ __launch_bounds__(256) void kan2_kernel(
    const unsigned short* __restrict__ l1, const float* __restrict__ bw,
    const float* __restrict__ sw, const float* __restrict__ sc,
    float* __restrict__ out)
{
    __shared__ __align__(16) unsigned short sW[2 * H * 8];   // 24.6 KB bf16 (sc folded)
    __shared__ unsigned int sB2[H];                          // 3 KB packed bf16 pairs

    const int t = threadIdx.x;
#pragma unroll
    for (int c = 0; c < 6; ++c) {
        int idx = t + c * 256;                 // 0..1535: o = idx/H, i = idx%H
        int o = (idx >= H) ? 1 : 0;
        int i = idx - o * H;
        float s = sc[(size_t)o * H + i];
        const float4* q = (const float4*)(sw + ((size_t)o * H + i) * 8);
        float4 w0 = q[0], w1 = q[1];
        uint4 pk;
        pk.x = pack2(f2bf(w0.x * s), f2bf(w0.y * s));
        pk.y = pack2(f2bf(w0.z * s), f2bf(w0.w * s));
        pk.z = pack2(f2bf(w1.x * s), f2bf(w1.y * s));
        pk.w = pack2(f2bf(w1.z * s), f2bf(w1.w * s));
        *(uint4*)&sW[(size_t)idx * 8] = pk;
    }
#pragma unroll
    for (int c = 0; c < 3; ++c) {
        int i = t + c * 256;
        sB2[i] = pack2(f2bf(bw[i]), f2bf(bw[H + i]));
    }
    __syncthreads();

    const int lane = t & 63;
    const int wv = t >> 6;
#pragma unroll 1
    for (int r = 0; r < 4; ++r) {
        const int n = blockIdx.x * R2 + wv * 4 + r;
        float a0 = 0.f, a1 = 0.f;
#pragma unroll
        for (int ii = 0; ii < H / 64; ++ii) {
            int i = lane + ii * 64;
            float h = bf2f(l1[(size_t)n * H + i]);
            float u = gelu_fast(h);
            float f0 = silu_f(u);
            float bb[8];
            kan_bases(u, bb);
            unsigned int bp = sB2[i];
            float bw0 = bf2f((unsigned short)(bp & 0xffffu));
            float bw1 = bf2f((unsigned short)(bp >> 16));
            bhalf8 w0 = *(const bhalf8*)&sW[(size_t)i * 8];
            bhalf8 w1 = *(const bhalf8*)&sW[(size_t)(H + i) * 8];
            float t0 = 0.f, t1 = 0.f;
#pragma unroll
            for (int c = 0; c < 8; ++c) {
                t0 = fmaf(bb[c], bf2f((unsigned short)w0[c]), t0);
                t1 = fmaf(bb[c], bf2f((unsigned short)w1[c]), t1);
            }
            a0 += fmaf(f0, bw0, t0);
            a1 += fmaf(f0, bw1, t1);
        }
#pragma unroll
        for (int off = 32; off > 0; off >>= 1) {
            a0 += __shfl_down(a0, off, 64);
            a1 += __shfl_down(a1, off, 64);
        }
        if (lane == 0) {
            out[(size_t)n * 2 + 0] = a0;
            out[(size_t)n * 2 + 1] = a1;
        }
    }
}

extern "C" void kernel_launch(void* const* d_in, const int* in_sizes, int n_in,
                              void* d_out, int out_size, void* d_ws, size_t ws_size,
                              hipStream_t stream) {
    const float* hidden = (const float*)d_in[0];
    const float* bw1    = (const float*)d_in[1];
    const float* sw1    = (const float*)d_in[2];
    const float* sc1    = (const float*)d_in[3];
    const float* bw2    = (const float*)d_in[4];
    const float* sw2    = (const float*)d_in[5];
    const float* sc2    = (const float*)d_in[6];
    float* out = (float*)d_out;

    const size_t l1_elems = (size_t)NROWS * H;     // 25.2 MB bf16
    const size_t wp_elems = (size_t)H * KEXP;      // 10.6 MB bf16
    unsigned short* l1 = (unsigned short*)d_ws;
    unsigned short* wp = l1 + l1_elems;
    unsigned short* F  = wp + wp_elems;            // 226.5 MB bf16

    prep_flat<<<3 * NROWS + H, 256, 0, stream>>>(hidden, bw1, sw1, sc1, wp, F);
    kan1_gemm<<<256, 512, 0, stream>>>(F, wp, l1);
    kan2_kernel<<<NROWS / R2, 256, 0, stream>>>(l1, bw2, sw2, sc2, out);
}

// Round 4
// 386.215 us; speedup vs baseline: 1.0271x; 1.0271x over previous
//
#include <hip/hip_runtime.h>
#include <math.h>

// Problem constants
#define NROWS 16384   // 32*512
#define H     768
#define KEXP  6912    // 768 (silu*base_w) + 768*8 (bases*spline_w*scaler)
#define NCHUNK 108    // KEXP/64 K-steps

typedef __attribute__((ext_vector_type(8))) short  bhalf8;
typedef __attribute__((ext_vector_type(4))) float  floatx4;
typedef __attribute__((ext_vector_type(4))) unsigned int uintx4;

__device__ __forceinline__ unsigned short f2bf(float f) {
    unsigned int u = __float_as_uint(f);
    u = (u + 0x7FFFu + ((u >> 16) & 1u)) >> 16;   // RNE
    return (unsigned short)u;
}
__device__ __forceinline__ float bf2f(unsigned short h) {
    return __uint_as_float(((unsigned int)h) << 16);
}
__device__ __forceinline__ unsigned int pack2(unsigned short a, unsigned short b) {
    return (unsigned int)a | ((unsigned int)b << 16);
}
__device__ __forceinline__ float silu_f(float x) { return x / (1.0f + __expf(-x)); }

// Branch-free tanh-form GELU (|err vs exact erf-GELU| < ~1e-3 in u)
__device__ __forceinline__ float gelu_fast(float x) {
    float x3 = x * x * x;
    float y = fmaf(x3, 0.0356774081f, x * 0.7978845608f);
    float e = __expf(2.0f * y);
    float th = 1.0f - 2.0f / (e + 1.0f);
    return 0.5f * x * (1.0f + th);
}

// Closed-form cubic B-spline bases on uniform knots g[j] = (j-3)*0.4 - 1.
__device__ __forceinline__ void kan_bases(float x, float* __restrict__ b) {
    const float c6 = 0.166666666667f;
    float u  = fmaf(x, 2.5f, 5.5f);
    float fj = floorf(u);
    float t  = u - fj;
    int  j0  = (int)fj;
    float t2 = t * t, t3 = t2 * t;
    float n0 = t3 * c6;
    float n1 = fmaf(t3, -0.5f, fmaf(t2, 0.5f, fmaf(t, 0.5f, c6)));
    float n2 = fmaf(t3, 0.5f, fmaf(t2, -1.0f, 0.666666666667f));
    float omt = 1.0f - t;
    float n3 = omt * omt * omt * c6;
#pragma unroll
    for (int c = 0; c < 8; ++c) {
        int d = j0 - c;
        float v = (d == 0) ? n0 : 0.0f;
        v = (d == 1) ? n1 : v;
        v = (d == 2) ? n2 : v;
        v = (d == 3) ? n3 : v;
        b[c] = v;
    }
}

// In-register granule expansion: x -> 8 bf16 basis slots (16B), placed by a
// branchless 128-bit shift. Window-clip at [0,128) bits == the select over
// c in [0,7] (verified per j0 case: nd lands at slot j0-d, out-of-range drops).
// Polynomial lines identical to kan_bases -> bitwise-identical bf16 output.
__device__ __forceinline__ uintx4 expand_granule(float xv) {
    const float c6 = 0.166666666667f;
    float u  = fmaf(xv, 2.5f, 5.5f);
    float fj = floorf(u);
    float t  = u - fj;
    int  j0  = (int)fj;
    float t2 = t * t, t3 = t2 * t;
    float n0 = t3 * c6;
    float n1 = fmaf(t3, -0.5f, fmaf(t2, 0.5f, fmaf(t, 0.5f, c6)));
    float n2 = fmaf(t3, 0.5f, fmaf(t2, -1.0f, 0.666666666667f));
    float omt = 1.0f - t;
    float n3 = omt * omt * omt * c6;
    unsigned long long P = (unsigned long long)pack2(f2bf(n3), f2bf(n2))
                         | ((unsigned long long)pack2(f2bf(n1), f2bf(n0)) << 32);
    int sh = 16 * (j0 - 3);                 // bit offset of n3 in the 128-bit window
    bool a0 = (sh >= 0) & (sh < 64);
    bool a1 = (sh >= 64) & (sh < 128);
    bool a2 = (sh > -64) & (sh < 0);
    int shl = sh & 63;
    unsigned long long t0  = P << shl;
    unsigned long long t0h = shl ? (P >> (64 - shl)) : 0ull;
    unsigned long long t1  = P << ((sh - 64) & 63);
    unsigned long long t2l = P >> ((-sh) & 63);
    unsigned long long lo = a0 ? t0  : (a2 ? t2l : 0ull);
    unsigned long long hi = a0 ? t0h : (a1 ? t1  : 0ull);
    uintx4 o;
    o.x = (unsigned int)lo; o.y = (unsigned int)(lo >> 32);
    o.z = (unsigned int)hi; o.w = (unsigned int)(hi >> 32);
    return o;
}

// ---- prep_sw: S = silu(x) bf16 (blocks 0..6143, pure elementwise streaming)
//      and W' bf16 [768][6912] (blocks 6144..6911, round-2 code verbatim).
__global__ __launch_bounds__(256) void prep_sw(
    const float* __restrict__ x, const float* __restrict__ bw,
    const float* __restrict__ sw, const float* __restrict__ sc,
    unsigned short* __restrict__ wp, unsigned short* __restrict__ S)
{
    const int b = blockIdx.x, t = threadIdx.x;
    if (b < 6144) {
        const size_t i = ((size_t)b * 256 + t) * 8;
        const float4* xp = (const float4*)(x + i);
        float4 v0 = xp[0], v1 = xp[1];
        uint4 pk;
        pk.x = pack2(f2bf(silu_f(v0.x)), f2bf(silu_f(v0.y)));
        pk.y = pack2(f2bf(silu_f(v0.z)), f2bf(silu_f(v0.w)));
        pk.z = pack2(f2bf(silu_f(v1.x)), f2bf(silu_f(v1.y)));
        pk.w = pack2(f2bf(silu_f(v1.z)), f2bf(silu_f(v1.w)));
        *(uint4*)(S + i) = pk;
    } else {
        const int n = b - 6144;
        const float* bwr = bw + (size_t)n * H;
        unsigned short* out = wp + (size_t)n * KEXP;
        if (t < 96) {
            const float4* xp = (const float4*)(bwr + t * 8);
            float4 v0 = xp[0], v1 = xp[1];
            uint4 pk;
            pk.x = pack2(f2bf(v0.x), f2bf(v0.y));
            pk.y = pack2(f2bf(v0.z), f2bf(v0.w));
            pk.z = pack2(f2bf(v1.x), f2bf(v1.y));
            pk.w = pack2(f2bf(v1.z), f2bf(v1.w));
            *(uint4*)(out + t * 8) = pk;
        }
#pragma unroll
        for (int p = 0; p < 3; ++p) {
            int i = t + p * 256;
            float s = sc[(size_t)n * H + i];
            const float4* swp = (const float4*)(sw + ((size_t)n * H + i) * 8);
            float4 w0 = swp[0], w1 = swp[1];
            uint4 pk;
            pk.x = pack2(f2bf(w0.x * s), f2bf(w0.y * s));
            pk.y = pack2(f2bf(w0.z * s), f2bf(w0.w * s));
            pk.z = pack2(f2bf(w1.x * s), f2bf(w1.y * s));
            pk.w = pack2(f2bf(w1.z * s), f2bf(w1.w * s));
            *(uint4*)(out + H + (size_t)i * 8) = pk;
        }
    }
}

// ==== Layer 1: 256x192 fused-expansion GEMM, 256 blocks = 1/CU ====
// kan1 is LDS-read-BW-bound (~176KB ds_read/K-step/CU ~= 3490cyc observed), so
// the win is deleting the F round-trip, not retiling. A-tiles for kc>=12 derive
// from 8 x-cols: load x->regs (1 dwordx4/thread/K-step), expand 4 granules,
// ds_write_b128 into the same XOR-swizzled layout (LDS write traffic replaces
// the gload_lds DMA writes 1:1). First 12 K-steps (silu region) stage from S.
// Steady state: exactly 1 VMEM op per phase (Ph1: X(k+2), Ph2/3/4: B(k+2));
// gates: vmcnt(5)@Ph2-end (retires X(k+1),B1(k)), vmcnt(6)@Ph4-end (B0(k+1)).
// ds_write publication: writer drains lgkmcnt(0) at its Ph3 PH_MID, first read
// is >=2 barriers later. Tail: stages predicated off (uniform, no barriers).

#define AS1 __attribute__((address_space(1)))
#define AS3 __attribute__((address_space(3)))

#define DSR(D, A, O) asm volatile("ds_read_b128 %0, %1 offset:" #O : "=v"(D) : "v"(A) : "memory")
#define DSW(A, D, O) asm volatile("ds_write_b128 %0, %1 offset:" #O :: "v"(A), "v"(D) : "memory")
#define LDA0(O) do{ DSR(fA0[0],avA[0],O); DSR(fA0[1],avA[1],O); DSR(fA0[2],avA[2],O); DSR(fA0[3],avA[3],O); \
                    DSR(fA0[4],avA[4],O); DSR(fA0[5],avA[5],O); DSR(fA0[6],avA[6],O); DSR(fA0[7],avA[7],O); }while(0)
#define LDA1(O) do{ DSR(fA1[0],avA[0],O); DSR(fA1[1],avA[1],O); DSR(fA1[2],avA[2],O); DSR(fA1[3],avA[3],O); \
                    DSR(fA1[4],avA[4],O); DSR(fA1[5],avA[5],O); DSR(fA1[6],avA[6],O); DSR(fA1[7],avA[7],O); }while(0)
#define LDB(O)  do{ DSR(fB[0],avB[0],O); DSR(fB[1],avB[1],O); }while(0)

#define MM0(QN) do{ \
    _Pragma("unroll") \
    for (int kk = 0; kk < 2; ++kk) \
        _Pragma("unroll") \
        for (int im = 0; im < 4; ++im) \
            acc0[QN][im] = __builtin_amdgcn_mfma_f32_16x16x32_bf16( \
                fA0[im*2+kk], fB[kk], acc0[QN][im], 0, 0, 0); \
}while(0)
#define MM1(QN) do{ \
    _Pragma("unroll") \
    for (int kk = 0; kk < 2; ++kk) \
        _Pragma("unroll") \
        for (int im = 0; im < 4; ++im) \
            acc1[QN][im] = __builtin_amdgcn_mfma_f32_16x16x32_bf16( \
                fA1[im*2+kk], fB[kk], acc1[QN][im], 0, 0, 0); \
}while(0)

#define STG_SA(BF,HH,KS) do{ \
    __builtin_amdgcn_global_load_lds((const AS1 void*)(pS##HH[0] + (size_t)(KS)*64), \
        (AS3 void*)&sA[BF][HH][wb8], 16, 0, 0); \
    __builtin_amdgcn_global_load_lds((const AS1 void*)(pS##HH[1] + (size_t)(KS)*64), \
        (AS3 void*)&sA[BF][HH][4096 + wb8], 16, 0, 0); \
}while(0)
#define STG_B(BF,QN,KS) \
    __builtin_amdgcn_global_load_lds((const AS1 void*)(pB[QN] + (size_t)(KS)*64), \
        (AS3 void*)&sB[BF][QN][wb8], 16, 0, 0)

#define EXPAND(XV, O) do{ \
    uintx4 g0 = expand_granule(XV.x); \
    uintx4 g1 = expand_granule(XV.y); \
    uintx4 g2 = expand_granule(XV.z); \
    uintx4 g3 = expand_granule(XV.w); \
    DSW(aw0, g0, O); DSW(aw1, g1, O); DSW(aw2, g2, O); DSW(aw3, g3, O); \
}while(0)

#define PH_MID do{ __builtin_amdgcn_s_barrier(); \
    asm volatile("s_waitcnt lgkmcnt(0)" ::: "memory"); \
    __builtin_amdgcn_sched_barrier(0); \
    __builtin_amdgcn_s_setprio(1); }while(0)
#define PH_END do{ __builtin_amdgcn_s_setprio(0); \
    __builtin_amdgcn_sched_barrier(0); \
    __builtin_amdgcn_s_barrier(); }while(0)
#define PH_END_VMN(N) do{ __builtin_amdgcn_s_setprio(0); \
    __builtin_amdgcn_sched_barrier(0); \
    asm volatile("s_waitcnt vmcnt(" #N ")" ::: "memory"); \
    __builtin_amdgcn_s_barrier(); }while(0)

__global__ __launch_bounds__(512, 1) void kan1_fused(
    const unsigned short* __restrict__ S, const float* __restrict__ x,
    const unsigned short* __restrict__ wp, unsigned short* __restrict__ l1)
{
    __shared__ __align__(16) unsigned short sA[2][2][8192];  // [buf][half 128rows][128*64]
    __shared__ __align__(16) unsigned short sB[2][3][4096];  // [buf][third 64rows][64*64]

    const int b = blockIdx.x;                  // 0..255
    const int s = b >> 3;
    const int rowT = (b & 7) * 8 + (s >> 2);   // 0..63
    const int colT = s & 3;                    // 0..3
    const int rowBase = rowT * 256, colBase = colT * 192;

    const int t = threadIdx.x;
    const int lane = t & 63;
    const int quad = lane >> 4, lm = lane & 15, p7 = lane & 7;
    const int wv = t >> 6, wr = wv & 1, wc = wv >> 1;   // 2M x 4N wave grid

    // DMA staging geometry (unchanged): granule t; row rr, slot XOR-swizzled
    const int rr = t >> 3;                    // 0..63
    const int slotx = (t & 7) ^ (rr & 7);
    const int wb8 = (t & 448) * 8;            // wave-uniform LDS elem base

    const unsigned short* pS0[2]; const unsigned short* pS1[2];
    const unsigned short* pB[3];
#pragma unroll
    for (int p = 0; p < 2; ++p) {
        pS0[p] = S + (size_t)(rowBase +       p*64 + rr) * H + slotx*8;
        pS1[p] = S + (size_t)(rowBase + 128 + p*64 + rr) * H + slotx*8;
    }
#pragma unroll
    for (int q = 0; q < 3; ++q)
        pB[q] = wp + (size_t)(colBase + q*64 + rr) * KEXP + slotx*8;

    // expansion geometry: thread t -> row r=t>>1 (0..255), slices sb=(t&1)*4..+3
    const int er  = t >> 1;
    const int esb = (t & 1) * 4;
    const float* pX = x + (size_t)(rowBase + er) * H + esb;   // +4 f32 per slice grp

    unsigned int avA[8], avB[2];
    unsigned int aw0, aw1, aw2, aw3;
    {
        unsigned int aB = (unsigned int)(size_t)(AS3 unsigned short*)&sA[0][0][0];
        unsigned int bB = (unsigned int)(size_t)(AS3 unsigned short*)&sB[0][0][0];
#pragma unroll
        for (int im = 0; im < 4; ++im)
#pragma unroll
            for (int kk = 0; kk < 2; ++kk)
                avA[im*2+kk] = aB + (unsigned)(((wr*64 + im*16 + lm)*64 + (((kk*4+quad)^p7)*8)) * 2);
#pragma unroll
        for (int kk = 0; kk < 2; ++kk)
            avB[kk] = bB + (unsigned)(((wc*16 + lm)*64 + (((kk*4+quad)^p7)*8)) * 2);
        const int hh = er >> 7, rl = er & 127;
        aw0 = aB + (unsigned)(hh*16384 + rl*128 + (((esb+0)^(er&7))*16));
        aw1 = aB + (unsigned)(hh*16384 + rl*128 + (((esb+1)^(er&7))*16));
        aw2 = aB + (unsigned)(hh*16384 + rl*128 + (((esb+2)^(er&7))*16));
        aw3 = aB + (unsigned)(hh*16384 + rl*128 + (((esb+3)^(er&7))*16));
    }

    floatx4 acc0[3][4] = {};   // [qn][im], qm=0 rows
    floatx4 acc1[3][4] = {};   // qm=1 rows
    bhalf8 fA0[8], fA1[8], fB[2];

    // ======== Part 1: kc = 0..11 (silu region, A from S), simple dbuf ========
    STG_SA(0,0,0); STG_SA(0,1,0); STG_B(0,0,0); STG_B(0,1,0); STG_B(0,2,0);
    asm volatile("s_waitcnt vmcnt(0)" ::: "memory");
    __builtin_amdgcn_s_barrier();
#pragma unroll 1
    for (int ii = 0; ii < 6; ++ii) {
        const int ko = 2*ii + 1, kn = 2*ii + 2;
        // step 2*ii from buf0, prefetch ko -> buf1
        STG_SA(1,0,ko); STG_SA(1,1,ko); STG_B(1,0,ko); STG_B(1,1,ko); STG_B(1,2,ko);
        LDA0(0); LDB(0);      PH_MID; MM0(0);         PH_END;
        LDA1(16384);          PH_MID; MM1(0);         PH_END;
        LDB(8192);            PH_MID; MM1(1); MM0(1); PH_END;
        LDB(16384);           PH_MID; MM0(2); MM1(2); PH_END_VMN(0);
        // step ko from buf1, prefetch kn -> buf0 (skip when ko == 11)
        if (ii < 5) { STG_SA(0,0,kn); STG_SA(0,1,kn); STG_B(0,0,kn); STG_B(0,1,kn); STG_B(0,2,kn); }
        LDA0(32768); LDB(24576); PH_MID; MM0(0);         PH_END;
        LDA1(49152);             PH_MID; MM1(0);         PH_END;
        LDB(32768);              PH_MID; MM1(1); MM0(1); PH_END;
        LDB(40960);              PH_MID; MM0(2); MM1(2); PH_END_VMN(0);
    }

    // ======== Part 2 prologue: buf0 <- A(12),B(12); buf1 <- A(13),B(13) ========
    float4 xva = *(const float4*)(pX + 12*8 - 96);   // X(12)
    float4 xvb = *(const float4*)(pX + 13*8 - 96);   // X(13)
    STG_B(0,0,12); STG_B(0,1,12); STG_B(0,2,12);
    STG_B(1,0,13); STG_B(1,1,13); STG_B(1,2,13);
    EXPAND(xva, 0);        // A(12) -> buf0 (backend waits the x load precisely)
    EXPAND(xvb, 32768);    // A(13) -> buf1
    asm volatile("s_waitcnt vmcnt(0) lgkmcnt(0)" ::: "memory");
    __builtin_amdgcn_s_barrier();

    // ======== Part 2: kc = 12..107, fused expansion, 1 VMEM op/phase ========
#pragma unroll 1
    for (int i = 0; i < 48; ++i) {
        const int ke = 12 + 2*i, ko = ke + 1;
        const int k2e = ke + 2, k2o = ko + 2;
        const bool pe = (k2e <= 107), po = (k2o <= 107);
        // ---- step ke (buf0); expand X(ko)=xvb -> buf1; issue X(k2e) -> xva
        LDA0(0); LDB(0);
        if (pe) xva = *(const float4*)(pX + (size_t)k2e*8 - 96);
                               PH_MID; MM0(0);         PH_END;
        LDA1(16384);
        if (pe) STG_B(0,0,k2e); PH_MID; MM1(0);        PH_END_VMN(5);
        LDB(8192);
        if (pe) STG_B(0,1,k2e);
        EXPAND(xvb, 32768);     PH_MID; MM1(1); MM0(1); PH_END;
        LDB(16384);
        if (pe) STG_B(0,2,k2e); PH_MID; MM0(2); MM1(2); PH_END_VMN(6);
        // ---- step ko (buf1); expand X(k2e)=xva -> buf0; issue X(k2o) -> xvb
        LDA0(32768); LDB(24576);
        if (po) xvb = *(const float4*)(pX + (size_t)k2o*8 - 96);
                               PH_MID; MM0(0);         PH_END;
        LDA1(49152);
        if (po) STG_B(1,0,k2o); PH_MID; MM1(0);        PH_END_VMN(5);
        LDB(32768);
        if (po) STG_B(1,1,k2o);
        if (pe) { EXPAND(xva, 0); }
                               PH_MID; MM1(1); MM0(1); PH_END;
        LDB(40960);
        if (po) STG_B(1,2,k2o); PH_MID; MM0(2); MM1(2); PH_END_VMN(6);
    }

    // epilogue: C layout col=lane&15, row=quad*4+reg (unchanged)
#pragma unroll
    for (int qn = 0; qn < 3; ++qn)
#pragma unroll
    for (int im = 0; im < 4; ++im) {
        const int col = colBase + qn*64 + wc*16 + lm;
        {
            const int row0 = rowBase + wr*64 + im*16 + quad*4;
#pragma unroll
            for (int rg = 0; rg < 4; ++rg)
                l1[(size_t)(row0 + rg) * H + col] = f2bf(acc0[qn][im][rg]);
        }
        {
            const int row0 = rowBase + 128 + wr*64 + im*16 + quad*4;
#pragma unroll
            for (int rg = 0; rg < 4; ++rg)
                l1[(size_t)(row0 + rg) * H + col] = f2bf(acc1[qn][im][rg]);
        }
    }
}

// ---- Layer 2: round-2 known-good version (4 rows/block, wave per row)
__global__ __launch_bounds__(256) void kan2_kernel(
    const unsigned short* __restrict__ l1, const float* __restrict__ bw,
    const float* __restrict__ sw, const float* __restrict__ sc,
    float* __restrict__ out)
{
    const int lane = threadIdx.x & 63;
    const int wv = threadIdx.x >> 6;
    const int n = blockIdx.x * 4 + wv;
    float a0 = 0.f, a1 = 0.f;
#pragma unroll
    for (int ii = 0; ii < H / 64; ++ii) {
        int i = lane + ii * 64;
        float h = bf2f(l1[(size_t)n * H + i]);
        float u = gelu_fast(h);
        float f0 = silu_f(u);
        float bb[8];
        kan_bases(u, bb);
        float bw0 = bw[i], bw1 = bw[H + i];
        float s0 = sc[i], s1 = sc[H + i];
        const float4* q0 = (const float4*)(sw + (size_t)i * 8);
        const float4* q1 = (const float4*)(sw + (size_t)(H + i) * 8);
        float4 w00 = q0[0], w01 = q0[1];
        float4 w10 = q1[0], w11 = q1[1];
        float t0 = bb[0]*w00.x + bb[1]*w00.y + bb[2]*w00.z + bb[3]*w00.w
                 + bb[4]*w01.x + bb[5]*w01.y + bb[6]*w01.z + bb[7]*w01.w;
        float t1 = bb[0]*w10.x + bb[1]*w10.y + bb[2]*w10.z + bb[3]*w10.w
                 + bb[4]*w11.x + bb[5]*w11.y + bb[6]*w11.z + bb[7]*w11.w;
        a0 += f0 * bw0 + s0 * t0;
        a1 += f0 * bw1 + s1 * t1;
    }
#pragma unroll
    for (int off = 32; off > 0; off >>= 1) {
        a0 += __shfl_down(a0, off, 64);
        a1 += __shfl_down(a1, off, 64);
    }
    if (lane == 0) {
        out[(size_t)n * 2 + 0] = a0;
        out[(size_t)n * 2 + 1] = a1;
    }
}

extern "C" void kernel_launch(void* const* d_in, const int* in_sizes, int n_in,
                              void* d_out, int out_size, void* d_ws, size_t ws_size,
                              hipStream_t stream) {
    const float* hidden = (const float*)d_in[0];
    const float* bw1    = (const float*)d_in[1];
    const float* sw1    = (const float*)d_in[2];
    const float* sc1    = (const float*)d_in[3];
    const float* bw2    = (const float*)d_in[4];
    const float* sw2    = (const float*)d_in[5];
    const float* sc2    = (const float*)d_in[6];
    float* out = (float*)d_out;

    const size_t l1_elems = (size_t)NROWS * H;     // 25.2 MB bf16
    const size_t wp_elems = (size_t)H * KEXP;      // 10.6 MB bf16
    unsigned short* l1 = (unsigned short*)d_ws;
    unsigned short* wp = l1 + l1_elems;
    unsigned short* S  = wp + wp_elems;            // 25.2 MB bf16 (silu(x))

    prep_sw<<<6144 + H, 256, 0, stream>>>(hidden, bw1, sw1, sc1, wp, S);
    kan1_fused<<<256, 512, 0, stream>>>(S, hidden, wp, l1);
    kan2_kernel<<<NROWS / 4, 256, 0, stream>>>(l1, bw2, sw2, sc2, out);
}

// Round 5
// 330.491 us; speedup vs baseline: 1.2003x; 1.1686x over previous
//
#include <hip/hip_runtime.h>
#include <math.h>

// Problem constants
#define NROWS 16384   // 32*512
#define H     768
#define KEXP  6912    // 768 (silu*base_w) + 768*8 (bases*spline_w*scaler)
#define NCHUNK 108    // KEXP/64 K-steps
#define NITER 54      // 2 K-steps per iteration

typedef __attribute__((ext_vector_type(8))) short  bhalf8;
typedef __attribute__((ext_vector_type(4))) float  floatx4;

__device__ __forceinline__ unsigned short f2bf(float f) {
    unsigned int u = __float_as_uint(f);
    u = (u + 0x7FFFu + ((u >> 16) & 1u)) >> 16;   // RNE
    return (unsigned short)u;
}
__device__ __forceinline__ float bf2f(unsigned short h) {
    return __uint_as_float(((unsigned int)h) << 16);
}
__device__ __forceinline__ unsigned int pack2(unsigned short a, unsigned short b) {
    return (unsigned int)a | ((unsigned int)b << 16);
}
__device__ __forceinline__ float silu_f(float x) { return x / (1.0f + __expf(-x)); }

// Branch-free tanh-form GELU (|err vs exact erf-GELU| < ~1e-3 in u)
__device__ __forceinline__ float gelu_fast(float x) {
    float x3 = x * x * x;
    float y = fmaf(x3, 0.0356774081f, x * 0.7978845608f);
    float e = __expf(2.0f * y);
    float th = 1.0f - 2.0f / (e + 1.0f);
    return 0.5f * x * (1.0f + th);
}

// Closed-form cubic B-spline bases on uniform knots g[j] = (j-3)*0.4 - 1.
__device__ __forceinline__ void kan_bases(float x, float* __restrict__ b) {
    const float c6 = 0.166666666667f;
    float u  = fmaf(x, 2.5f, 5.5f);
    float fj = floorf(u);
    float t  = u - fj;
    int  j0  = (int)fj;
    float t2 = t * t, t3 = t2 * t;
    float n0 = t3 * c6;
    float n1 = fmaf(t3, -0.5f, fmaf(t2, 0.5f, fmaf(t, 0.5f, c6)));
    float n2 = fmaf(t3, 0.5f, fmaf(t2, -1.0f, 0.666666666667f));
    float omt = 1.0f - t;
    float n3 = omt * omt * omt * c6;
#pragma unroll
    for (int c = 0; c < 8; ++c) {
        int d = j0 - c;
        float v = (d == 0) ? n0 : 0.0f;
        v = (d == 1) ? n1 : v;
        v = (d == 2) ? n2 : v;
        v = (d == 3) ? n3 : v;
        b[c] = v;
    }
}

// ---- prep_expand (flat): blocks 0..6143 expand F (2048 elems/block, 8 strided
//      elems/thread -> every store lane-consecutive; no LDS, no syncthreads).
//      Blocks 6144..6911: W' rows (round-2 code verbatim).
__global__ __launch_bounds__(256) void prep_expand(
    const float* __restrict__ x, const float* __restrict__ bw,
    const float* __restrict__ sw, const float* __restrict__ sc,
    unsigned short* __restrict__ wp, unsigned short* __restrict__ F)
{
    const int b = blockIdx.x, t = threadIdx.x;
    if (b < 6144) {
        const int e0 = b * 2048 + t;
#pragma unroll
        for (int j = 0; j < 8; ++j) {
            int e = e0 + j * 256;
            int n = e / 768;                      // magic-mul
            int i = e - n * 768;
            float xv = x[e];                      // x is row-major (N,768): linear in e
            unsigned short* out = F + (size_t)n * KEXP;
            out[i] = f2bf(silu_f(xv));            // 2B store, lane-consecutive
            float bb[8];
            kan_bases(xv, bb);
            uint4 pk;
            pk.x = pack2(f2bf(bb[0]), f2bf(bb[1]));
            pk.y = pack2(f2bf(bb[2]), f2bf(bb[3]));
            pk.z = pack2(f2bf(bb[4]), f2bf(bb[5]));
            pk.w = pack2(f2bf(bb[6]), f2bf(bb[7]));
            *(uint4*)(out + H + (size_t)i * 8) = pk;  // 16B store, lane-consecutive
        }
    } else {
        const int n = b - 6144;
        const float* bwr = bw + (size_t)n * H;
        unsigned short* out = wp + (size_t)n * KEXP;
        if (t < 96) {
            const float4* xp = (const float4*)(bwr + t * 8);
            float4 v0 = xp[0], v1 = xp[1];
            uint4 pk;
            pk.x = pack2(f2bf(v0.x), f2bf(v0.y));
            pk.y = pack2(f2bf(v0.z), f2bf(v0.w));
            pk.z = pack2(f2bf(v1.x), f2bf(v1.y));
            pk.w = pack2(f2bf(v1.z), f2bf(v1.w));
            *(uint4*)(out + t * 8) = pk;
        }
#pragma unroll
        for (int p = 0; p < 3; ++p) {
            int i = t + p * 256;
            float s = sc[(size_t)n * H + i];
            const float4* swp = (const float4*)(sw + ((size_t)n * H + i) * 8);
            float4 w0 = swp[0], w1 = swp[1];
            uint4 pk;
            pk.x = pack2(f2bf(w0.x * s), f2bf(w0.y * s));
            pk.y = pack2(f2bf(w0.z * s), f2bf(w0.w * s));
            pk.z = pack2(f2bf(w1.x * s), f2bf(w1.y * s));
            pk.w = pack2(f2bf(w1.z * s), f2bf(w1.w * s));
            *(uint4*)(out + H + (size_t)i * 8) = pk;
        }
    }
}

// ==== Layer 1: 256x192 GEMM, 3 uniform 16-MFMA phases per K-step ====
//
// Identical data flow / LDS layout / swizzle / fragments to the round-2 kernel
// (157us); only barrier placement + stage distribution changed. Model: per-SIMD
// matrix time = 96 MFMA x 19.4cyc = 1862 cyc/K-step; r2 measured 3490 -> the gap
// is 4 barrier-pairs with two 8-MFMA phases. 3 phases x 16 MFMA amortize better.
// Phases (buf b): Ph1 {LDA0,LDA1,LDB(B0) -> MM0(0);MM1(0)}
//                 Ph2 {LDB(B1) -> MM0(1);MM1(1)}  Ph3 {LDB(B2) -> MM0(2);MM1(2)}
// Region last reads: A0,A1,B0 @Ph1; B1 @Ph2; B2 @Ph3 -> stages:
//   Ph1: B2(other-buf, k+1) | Ph2: A0,A1(k+2) | Ph3: B0,B1(k+2)
// Load positions per step: L1=B2 | L2..L5=A0a,A0b,A1a,A1b | L6,L7=B0,B1.
// Gates (positional, in-order retirement; never drain):
//   G1@Ph1-END vmcnt(8)  : retires B1(k)=L7(k-2)  [after it: 7(k-1)+L1(k)=8]
//   G2@Ph2-END vmcnt(11) : retires B2(k)=L1(k-1)  [after it: 6(k-1)+5(k)=11]
//   G3@Ph3-END vmcnt(8)  : retires A/B0(k+1)<=L6(k-1) [after: L7(k-1)+7(k)=8]
// Prologue issues step0 {A0a,A0b,A1a,A1b,B0,B1,B2} then step1 {A..,B0,B1}
// (13 loads) + vmcnt(8): makes steady gates exact from k=0.

#define AS1 __attribute__((address_space(1)))
#define AS3 __attribute__((address_space(3)))

#define DSR(D, A, O) asm volatile("ds_read_b128 %0, %1 offset:" #O : "=v"(D) : "v"(A) : "memory")
#define LDA0(O) do{ DSR(fA0[0],avA[0],O); DSR(fA0[1],avA[1],O); DSR(fA0[2],avA[2],O); DSR(fA0[3],avA[3],O); \
                    DSR(fA0[4],avA[4],O); DSR(fA0[5],avA[5],O); DSR(fA0[6],avA[6],O); DSR(fA0[7],avA[7],O); }while(0)
#define LDA1(O) do{ DSR(fA1[0],avA[0],O); DSR(fA1[1],avA[1],O); DSR(fA1[2],avA[2],O); DSR(fA1[3],avA[3],O); \
                    DSR(fA1[4],avA[4],O); DSR(fA1[5],avA[5],O); DSR(fA1[6],avA[6],O); DSR(fA1[7],avA[7],O); }while(0)
#define LDB(O)  do{ DSR(fB[0],avB[0],O); DSR(fB[1],avB[1],O); }while(0)

#define MM0(QN) do{ \
    _Pragma("unroll") \
    for (int kk = 0; kk < 2; ++kk) \
        _Pragma("unroll") \
        for (int im = 0; im < 4; ++im) \
            acc0[QN][im] = __builtin_amdgcn_mfma_f32_16x16x32_bf16( \
                fA0[im*2+kk], fB[kk], acc0[QN][im], 0, 0, 0); \
}while(0)
#define MM1(QN) do{ \
    _Pragma("unroll") \
    for (int kk = 0; kk < 2; ++kk) \
        _Pragma("unroll") \
        for (int im = 0; im < 4; ++im) \
            acc1[QN][im] = __builtin_amdgcn_mfma_f32_16x16x32_bf16( \
                fA1[im*2+kk], fB[kk], acc1[QN][im], 0, 0, 0); \
}while(0)

#define STG_A(BF,HH,KS) do{ \
    __builtin_amdgcn_global_load_lds((const AS1 void*)(pA##HH[0] + (size_t)(KS)*64), \
        (AS3 void*)&sA[BF][HH][wb8], 16, 0, 0); \
    __builtin_amdgcn_global_load_lds((const AS1 void*)(pA##HH[1] + (size_t)(KS)*64), \
        (AS3 void*)&sA[BF][HH][4096 + wb8], 16, 0, 0); \
}while(0)
#define STG_B(BF,QN,KS) \
    __builtin_amdgcn_global_load_lds((const AS1 void*)(pB[QN] + (size_t)(KS)*64), \
        (AS3 void*)&sB[BF][QN][wb8], 16, 0, 0)

#define PH_MID do{ __builtin_amdgcn_s_barrier(); \
    asm volatile("s_waitcnt lgkmcnt(0)" ::: "memory"); \
    __builtin_amdgcn_sched_barrier(0); \
    __builtin_amdgcn_s_setprio(1); }while(0)
#define PH_END_VMN(N) do{ __builtin_amdgcn_s_setprio(0); \
    __builtin_amdgcn_sched_barrier(0); \
    asm volatile("s_waitcnt vmcnt(" #N ")" ::: "memory"); \
    __builtin_amdgcn_s_barrier(); }while(0)

__global__ __launch_bounds__(512, 2) void kan1_gemm(
    const unsigned short* __restrict__ F, const unsigned short* __restrict__ wp,
    unsigned short* __restrict__ l1)
{
    __shared__ __align__(16) unsigned short sA[2][2][8192];  // [buf][half 128rows][128*64]
    __shared__ __align__(16) unsigned short sB[2][3][4096];  // [buf][third 64rows][64*64]

    const int b = blockIdx.x;                  // 0..255
    const int s = b >> 3;
    const int rowT = (b & 7) * 8 + (s >> 2);   // 0..63
    const int colT = s & 3;                    // 0..3
    const int rowBase = rowT * 256, colBase = colT * 192;

    const int t = threadIdx.x;
    const int lane = t & 63;
    const int quad = lane >> 4, lm = lane & 15, p7 = lane & 7;
    const int wv = t >> 6, wr = wv & 1, wc = wv >> 1;   // 2M x 4N wave grid

    const int rr = t >> 3;                    // 0..63
    const int slotx = (t & 7) ^ (rr & 7);
    const int wb8 = (t & 448) * 8;            // wave-uniform LDS elem base (wv*512)

    const unsigned short* pA0[2]; const unsigned short* pA1[2];
    const unsigned short* pB[3];
#pragma unroll
    for (int p = 0; p < 2; ++p) {
        pA0[p] = F + (size_t)(rowBase +       p*64 + rr) * KEXP + slotx*8;
        pA1[p] = F + (size_t)(rowBase + 128 + p*64 + rr) * KEXP + slotx*8;
    }
#pragma unroll
    for (int q = 0; q < 3; ++q)
        pB[q] = wp + (size_t)(colBase + q*64 + rr) * KEXP + slotx*8;

    unsigned int avA[8], avB[2];
    {
        unsigned int aB = (unsigned int)(size_t)(AS3 unsigned short*)&sA[0][0][0];
        unsigned int bB = (unsigned int)(size_t)(AS3 unsigned short*)&sB[0][0][0];
#pragma unroll
        for (int im = 0; im < 4; ++im)
#pragma unroll
            for (int kk = 0; kk < 2; ++kk)
                avA[im*2+kk] = aB + (unsigned)(((wr*64 + im*16 + lm)*64 + (((kk*4+quad)^p7)*8)) * 2);
#pragma unroll
        for (int kk = 0; kk < 2; ++kk)
            avB[kk] = bB + (unsigned)(((wc*16 + lm)*64 + (((kk*4+quad)^p7)*8)) * 2);
    }

    floatx4 acc0[3][4] = {};   // [qn][im], qm=0 rows
    floatx4 acc1[3][4] = {};   // qm=1 rows
    bhalf8 fA0[8], fA1[8], fB[2];

    // prologue: step0 {A0a,A0b,A1a,A1b,B0,B1,B2} then step1 {A.., B0, B1}
    STG_A(0,0,0); STG_A(0,1,0); STG_B(0,0,0); STG_B(0,1,0); STG_B(0,2,0);
    STG_A(1,0,1); STG_A(1,1,1); STG_B(1,0,1); STG_B(1,1,1);
    asm volatile("s_waitcnt vmcnt(8)" ::: "memory");
    __builtin_amdgcn_s_barrier();

#pragma unroll 1
    for (int i = 0; i < NITER; ++i) {
        const int k1 = 2*i + 1;
        const int k2 = (2*i + 2 > 107) ? 107 : 2*i + 2;
        const int k3 = (2*i + 3 > 107) ? 107 : 2*i + 3;
        // ---- K-step 2i (buf0)
        LDA0(0); LDA1(16384); LDB(0);
        STG_B(1,2,k1);                 PH_MID; MM0(0); MM1(0); PH_END_VMN(8);
        LDB(8192);
        STG_A(0,0,k2); STG_A(0,1,k2);  PH_MID; MM0(1); MM1(1); PH_END_VMN(11);
        LDB(16384);
        STG_B(0,0,k2); STG_B(0,1,k2);  PH_MID; MM0(2); MM1(2); PH_END_VMN(8);
        // ---- K-step 2i+1 (buf1)
        LDA0(32768); LDA1(49152); LDB(24576);
        STG_B(0,2,k2);                 PH_MID; MM0(0); MM1(0); PH_END_VMN(8);
        LDB(32768);
        STG_A(1,0,k3); STG_A(1,1,k3);  PH_MID; MM0(1); MM1(1); PH_END_VMN(11);
        LDB(40960);
        STG_B(1,0,k3); STG_B(1,1,k3);  PH_MID; MM0(2); MM1(2); PH_END_VMN(8);
    }

    // epilogue: C layout col=lane&15, row=quad*4+reg
#pragma unroll
    for (int qn = 0; qn < 3; ++qn)
#pragma unroll
    for (int im = 0; im < 4; ++im) {
        const int col = colBase + qn*64 + wc*16 + lm;
        {
            const int row0 = rowBase + wr*64 + im*16 + quad*4;
#pragma unroll
            for (int rg = 0; rg < 4; ++rg)
                l1[(size_t)(row0 + rg) * H + col] = f2bf(acc0[qn][im][rg]);
        }
        {
            const int row0 = rowBase + 128 + wr*64 + im*16 + quad*4;
#pragma unroll
            for (int rg = 0; rg < 4; ++rg)
                l1[(size_t)(row0 + rg) * H + col] = f2bf(acc1[qn][im][rg]);
        }
    }
}

// ---- Layer 2: known-good round-0/2 version (4 rows/block, wave per row)
__global__ __launch_bounds__(256) void kan2_kernel(
    const unsigned short* __restrict__ l1, const float* __restrict__ bw,
    const float* __restrict__ sw, const float* __restrict__ sc,
    float* __restrict__ out)
{
    const int lane = threadIdx.x & 63;
    const int wv = threadIdx.x >> 6;
    const int n = blockIdx.x * 4 + wv;
    float a0 = 0.f, a1 = 0.f;
#pragma unroll
    for (int ii = 0; ii < H / 64; ++ii) {
        int i = lane + ii * 64;
        float h = bf2f(l1[(size_t)n * H + i]);
        float u = gelu_fast(h);
        float f0 = silu_f(u);
        float bb[8];
        kan_bases(u, bb);
        float bw0 = bw[i], bw1 = bw[H + i];
        float s0 = sc[i], s1 = sc[H + i];
        const float4* q0 = (const float4*)(sw + (size_t)i * 8);
        const float4* q1 = (const float4*)(sw + (size_t)(H + i) * 8);
        float4 w00 = q0[0], w01 = q0[1];
        float4 w10 = q1[0], w11 = q1[1];
        float t0 = bb[0]*w00.x + bb[1]*w00.y + bb[2]*w00.z + bb[3]*w00.w
                 + bb[4]*w01.x + bb[5]*w01.y + bb[6]*w01.z + bb[7]*w01.w;
        float t1 = bb[0]*w10.x + bb[1]*w10.y + bb[2]*w10.z + bb[3]*w10.w
                 + bb[4]*w11.x + bb[5]*w11.y + bb[6]*w11.z + bb[7]*w11.w;
        a0 += f0 * bw0 + s0 * t0;
        a1 += f0 * bw1 + s1 * t1;
    }
#pragma unroll
    for (int off = 32; off > 0; off >>= 1) {
        a0 += __shfl_down(a0, off, 64);
        a1 += __shfl_down(a1, off, 64);
    }
    if (lane == 0) {
        out[(size_t)n * 2 + 0] = a0;
        out[(size_t)n * 2 + 1] = a1;
    }
}

extern "C" void kernel_launch(void* const* d_in, const int* in_sizes, int n_in,
                              void* d_out, int out_size, void* d_ws, size_t ws_size,
                              hipStream_t stream) {
    const float* hidden = (const float*)d_in[0];
    const float* bw1    = (const float*)d_in[1];
    const float* sw1    = (const float*)d_in[2];
    const float* sc1    = (const float*)d_in[3];
    const float* bw2    = (const float*)d_in[4];
    const float* sw2    = (const float*)d_in[5];
    const float* sc2    = (const float*)d_in[6];
    float* out = (float*)d_out;

    const size_t l1_elems = (size_t)NROWS * H;     // 25.2 MB bf16
    const size_t wp_elems = (size_t)H * KEXP;      // 10.6 MB bf16
    unsigned short* l1 = (unsigned short*)d_ws;
    unsigned short* wp = l1 + l1_elems;
    unsigned short* F  = wp + wp_elems;            // 226.5 MB bf16

    prep_expand<<<6144 + H, 256, 0, stream>>>(hidden, bw1, sw1, sc1, wp, F);
    kan1_gemm<<<256, 512, 0, stream>>>(F, wp, l1);
    kan2_kernel<<<NROWS / 4, 256, 0, stream>>>(l1, bw2, sw2, sc2, out);
}